// Round 21
// baseline (202.737 us; speedup 1.0000x reference)
//
#include <hip/hip_runtime.h>
#include <hip/hip_bf16.h>
#include <cstdint>

#define D_ 1024
#define H_ 16
#define DH_ 64
#define FF_ 4096
#define B_ 2
#define S_ 2048
#define MR_ (B_ * S_)   // 4096 rows

typedef __bf16 bf16x8 __attribute__((ext_vector_type(8)));
typedef __bf16 bf16x4 __attribute__((ext_vector_type(4)));
typedef float f32x4 __attribute__((ext_vector_type(4)));
typedef float f32x16 __attribute__((ext_vector_type(16)));

// ---- async global->LDS, 16B per lane (linear dest in lane order) ----
__device__ __forceinline__ void g2lds16(const void* g, void* l) {
  __builtin_amdgcn_global_load_lds(
      (__attribute__((address_space(1))) void*)(uintptr_t)g,
      (__attribute__((address_space(3))) void*)(uint32_t)(uintptr_t)l,
      16, 0, 0);
}

// pack two f32 -> one u32 holding 2 bf16 (lo, hi)
__device__ __forceinline__ unsigned pkbf16(float lo, float hi) {
  unsigned r;
  asm("v_cvt_pk_bf16_f32 %0, %1, %2" : "=v"(r) : "v"(lo), "v"(hi));
  return r;
}

// raw v_exp_f32 (1 instr)
__device__ __forceinline__ float fexp2(float x) {
  return __builtin_amdgcn_exp2f(x);
}

// ==========  merged weight transpose + fp32->bf16 (all 4 weights, 1 dispatch) ======
__global__ __launch_bounds__(256) void transpose_all(
    const float* __restrict__ W0, __hip_bfloat16* __restrict__ T0,
    const float* __restrict__ W1p, __hip_bfloat16* __restrict__ T1,
    const float* __restrict__ W2p, __hip_bfloat16* __restrict__ T2,
    const float* __restrict__ W3p, __hip_bfloat16* __restrict__ T3) {
  __shared__ float t[32][33];
  int ti = blockIdx.x;
  const float* W;
  __hip_bfloat16* Wt;
  int K, N, loc;
  if (ti < 3072)      { W = W0;  Wt = T0; K = 1024; N = 3072; loc = ti; }
  else if (ti < 4096) { W = W1p; Wt = T1; K = 1024; N = 1024; loc = ti - 3072; }
  else if (ti < 8192) { W = W2p; Wt = T2; K = 1024; N = 4096; loc = ti - 4096; }
  else                { W = W3p; Wt = T3; K = 4096; N = 1024; loc = ti - 8192; }
  int ntn = N >> 5;
  int bx = (loc % ntn) * 32;   // n
  int by = (loc / ntn) * 32;   // k
  int tx = threadIdx.x & 31, ty = threadIdx.x >> 5;  // 32 x 8
#pragma unroll
  for (int i = 0; i < 4; ++i)
    t[ty + 8 * i][tx] = W[(size_t)(by + ty + 8 * i) * N + bx + tx];
  __syncthreads();
#pragma unroll
  for (int i = 0; i < 4; ++i)
    Wt[(size_t)(bx + ty + 8 * i) * K + by + tx] = __float2bfloat16(t[tx][ty + 8 * i]);
}

// ==========================  LayerNorm (fp32 in, bf16 out)  ========================
__global__ __launch_bounds__(256) void ln_kernel(
    const float* __restrict__ x, const float* __restrict__ g,
    const float* __restrict__ b, __hip_bfloat16* __restrict__ out) {
  int row = blockIdx.x;
  const float4* xr = (const float4*)(x + (size_t)row * D_);
  float4 v = xr[threadIdx.x];
  float s = v.x + v.y + v.z + v.w;
  float ss = v.x * v.x + v.y * v.y + v.z * v.z + v.w * v.w;
#pragma unroll
  for (int m = 1; m < 64; m <<= 1) {
    s += __shfl_xor(s, m);
    ss += __shfl_xor(ss, m);
  }
  __shared__ float rs[4], rss[4];
  int wave = threadIdx.x >> 6, lane = threadIdx.x & 63;
  if (lane == 0) { rs[wave] = s; rss[wave] = ss; }
  __syncthreads();
  s = rs[0] + rs[1] + rs[2] + rs[3];
  ss = rss[0] + rss[1] + rss[2] + rss[3];
  float mean = s * (1.0f / D_);
  float var = ss * (1.0f / D_) - mean * mean;
  float inv = rsqrtf(var + 1e-5f);
  int c = threadIdx.x * 4;
  float4 gv = ((const float4*)g)[threadIdx.x];
  float4 bv = ((const float4*)b)[threadIdx.x];
  __hip_bfloat16* o = out + (size_t)row * D_ + c;
  o[0] = __float2bfloat16((v.x - mean) * inv * gv.x + bv.x);
  o[1] = __float2bfloat16((v.y - mean) * inv * gv.y + bv.y);
  o[2] = __float2bfloat16((v.z - mean) * inv * gv.z + bv.z);
  o[3] = __float2bfloat16((v.w - mean) * inv * gv.w + bv.w);
}

// =======  GEMM4: 128x128 tile, 4 waves (2x2), per-wave 64x64 (MF=NF=4)  =============
// EPI 0: bf16 +bias;  1: f32 +bias+resid;  2: bf16 +bias+gelu;
// EPI 3: QKV fused — V cols (>=2D) -> vt transposed ([b,h,dh,s], packed bf16x4).
template <int EPI>
__global__ __launch_bounds__(256) void gemm4(
    const __hip_bfloat16* __restrict__ A, const __hip_bfloat16* __restrict__ Bt,
    const float* __restrict__ bias, const float* __restrict__ resid,
    void* __restrict__ outp, __hip_bfloat16* __restrict__ vt, int M, int N, int K) {
  constexpr int BM = 128, BN = 128, MF = 4, NF = 4;
  __shared__ alignas(16) __hip_bfloat16 sA[2][BM * 64];
  __shared__ alignas(16) __hip_bfloat16 sB[2][BN * 64];
  const int tid = threadIdx.x;                 // 0..255
  const int lane = tid & 63, wave = tid >> 6;  // 4 waves
  const int l15 = lane & 15, l4 = lane >> 4;
  const int wr = wave >> 1, wc = wave & 1;     // 2x2
  const int csw = (l15 & 7) << 3;

  const int gx = gridDim.x;
  int nwg = gx * gridDim.y;
  int flat = blockIdx.y * gx + blockIdx.x;
  int cpx = nwg >> 3;
  int swz = (flat & 7) * cpx + (flat >> 3);
  const int m0 = (swz / gx) * BM, n0 = (swz % gx) * BN;

  f32x4 z = {0.f, 0.f, 0.f, 0.f};
  f32x4 acc[MF][NF];
#pragma unroll
  for (int i = 0; i < MF; ++i)
#pragma unroll
    for (int j = 0; j < NF; ++j) acc[i][j] = z;

  auto stage = [&](int bu, int kt) {   // 4+4 VMEM instr / thread
#pragma unroll
    for (int it = 0; it < 4; ++it) {
      int idx = it * 256 + tid;
      int r = idx >> 3, c = (idx & 7) * 8;
      int cs = c ^ ((r & 7) << 3);
      g2lds16(A + (size_t)(m0 + r) * K + kt + cs, (void*)(&sA[bu][idx * 8]));
      g2lds16(Bt + (size_t)(n0 + r) * K + kt + cs, (void*)(&sB[bu][idx * 8]));
    }
  };

  const int nk = K / 64;
  stage(0, 0);
  asm volatile("s_waitcnt vmcnt(0)" ::: "memory");
  __builtin_amdgcn_s_barrier();

  for (int j = 0; j < nk; ++j) {
    const int cur = j & 1;
    if (j + 1 < nk) stage(cur ^ 1, (j + 1) * 64);

    __builtin_amdgcn_s_setprio(1);
#pragma unroll
    for (int kk = 0; kk < 2; ++kk) {
      int col = (kk * 32 + l4 * 8) ^ csw;
      bf16x8 bfr[NF];
#pragma unroll
      for (int nf = 0; nf < NF; ++nf)
        bfr[nf] = *(const bf16x8*)(&sB[cur][(wc * 64 + nf * 16 + l15) * 64 + col]);
#pragma unroll
      for (int mf = 0; mf < MF; ++mf) {
        bf16x8 af = *(const bf16x8*)(&sA[cur][(wr * 64 + mf * 16 + l15) * 64 + col]);
#pragma unroll
        for (int nf = 0; nf < NF; ++nf)
          acc[mf][nf] =
              __builtin_amdgcn_mfma_f32_16x16x32_bf16(af, bfr[nf], acc[mf][nf], 0, 0, 0);
      }
    }
    __builtin_amdgcn_s_setprio(0);

    asm volatile("s_waitcnt lgkmcnt(0)" ::: "memory");
    __builtin_amdgcn_sched_barrier(0);
    asm volatile("s_waitcnt vmcnt(0)" ::: "memory");
    __builtin_amdgcn_s_barrier();
    asm volatile("" ::: "memory");
  }

#pragma unroll
  for (int mf = 0; mf < MF; ++mf) {
#pragma unroll
    for (int nf = 0; nf < NF; ++nf) {
      int col = n0 + wc * 64 + nf * 16 + l15;
      float bv = bias[col];
      if (EPI == 3 && col >= 2 * D_) {
        int d = col - 2 * D_;
        int srow0 = m0 + wr * 64 + mf * 16 + l4 * 4;
        int bb = srow0 >> 11, s0 = srow0 & (S_ - 1);
        bf16x4 ov;
#pragma unroll
        for (int j = 0; j < 4; ++j) ov[j] = (__bf16)(acc[mf][nf][j] + bv);
        *(bf16x4*)(vt + ((size_t)(bb * H_ + (d >> 6)) * DH_ + (d & 63)) * S_ + s0) = ov;
      } else {
#pragma unroll
        for (int j = 0; j < 4; ++j) {
          int row = m0 + wr * 64 + mf * 16 + l4 * 4 + j;
          size_t o = (size_t)row * N + col;
          float v = acc[mf][nf][j] + bv;
          if (EPI == 0 || EPI == 3) {
            ((__hip_bfloat16*)outp)[o] = __float2bfloat16(v);
          } else if (EPI == 1) {
            ((float*)outp)[o] = v + resid[o];
          } else {
            float a = 0.7978845608028654f * (v + 0.044715f * v * v * v);
            a = fminf(fmaxf(a, -15.f), 15.f);
            float e = __expf(2.f * a);
            float th = (e - 1.f) / (e + 1.f);
            ((__hip_bfloat16*)outp)[o] = __float2bfloat16(0.5f * v * (1.f + th));
          }
        }
      }
    }
  }
}

// ====  GEMM64R3: 128x64 tile, 4 waves (2x2), 3-buffer ring + counted vmcnt(6)  ======
template <int EPI>
__global__ __launch_bounds__(256) void gemm64r3(
    const __hip_bfloat16* __restrict__ A, const __hip_bfloat16* __restrict__ Bt,
    const float* __restrict__ bias, const float* __restrict__ resid,
    void* __restrict__ outp, int M, int N, int K) {
  constexpr int BM = 128, BN = 64, MF = 4, NF = 2;
  __shared__ alignas(16) __hip_bfloat16 sA[3][BM * 64];
  __shared__ alignas(16) __hip_bfloat16 sB[3][BN * 64];
  const int tid = threadIdx.x;                 // 0..255
  const int lane = tid & 63, wave = tid >> 6;  // 4 waves
  const int l15 = lane & 15, l4 = lane >> 4;
  const int wr = wave >> 1, wc = wave & 1;     // 2x2
  const int csw = (l15 & 7) << 3;

  const int gx = gridDim.x;
  int nwg = gx * gridDim.y;
  int flat = blockIdx.y * gx + blockIdx.x;
  int cpx = nwg >> 3;
  int swz = (flat & 7) * cpx + (flat >> 3);
  const int m0 = (swz / gx) * BM, n0 = (swz % gx) * BN;

  f32x4 z = {0.f, 0.f, 0.f, 0.f};
  f32x4 acc[MF][NF];
#pragma unroll
  for (int i = 0; i < MF; ++i)
#pragma unroll
    for (int j = 0; j < NF; ++j) acc[i][j] = z;

  auto stage = [&](int bu, int kt) {   // 4+2 = 6 VMEM instr / thread
#pragma unroll
    for (int it = 0; it < 4; ++it) {
      int idx = it * 256 + tid;
      int r = idx >> 3, c = (idx & 7) * 8;
      int cs = c ^ ((r & 7) << 3);
      g2lds16(A + (size_t)(m0 + r) * K + kt + cs, (void*)(&sA[bu][idx * 8]));
    }
#pragma unroll
    for (int it = 0; it < 2; ++it) {
      int idx = it * 256 + tid;
      int r = idx >> 3, c = (idx & 7) * 8;
      int cs = c ^ ((r & 7) << 3);
      g2lds16(Bt + (size_t)(n0 + r) * K + kt + cs, (void*)(&sB[bu][idx * 8]));
    }
  };

  const int nk = K / 64;
  stage(0, 0);
  stage(1, 64);
  asm volatile("s_waitcnt vmcnt(6)" ::: "memory");
  __builtin_amdgcn_s_barrier();

  int bu = 0, bu2 = 2;
  for (int j = 0; j < nk; ++j) {
    const bool pf = (j + 2) < nk;
    if (pf) stage(bu2, (j + 2) * 64);

    __builtin_amdgcn_s_setprio(1);
#pragma unroll
    for (int kk = 0; kk < 2; ++kk) {
      int col = (kk * 32 + l4 * 8) ^ csw;
      bf16x8 bfr[NF];
#pragma unroll
      for (int nf = 0; nf < NF; ++nf)
        bfr[nf] = *(const bf16x8*)(&sB[bu][(wc * 32 + nf * 16 + l15) * 64 + col]);
#pragma unroll
      for (int mf = 0; mf < MF; ++mf) {
        bf16x8 af = *(const bf16x8*)(&sA[bu][(wr * 64 + mf * 16 + l15) * 64 + col]);
#pragma unroll
        for (int nf = 0; nf < NF; ++nf)
          acc[mf][nf] =
              __builtin_amdgcn_mfma_f32_16x16x32_bf16(af, bfr[nf], acc[mf][nf], 0, 0, 0);
      }
    }
    __builtin_amdgcn_s_setprio(0);

    asm volatile("s_waitcnt lgkmcnt(0)" ::: "memory");
    __builtin_amdgcn_sched_barrier(0);
    if (pf)
      asm volatile("s_waitcnt vmcnt(6)" ::: "memory");
    else
      asm volatile("s_waitcnt vmcnt(0)" ::: "memory");
    __builtin_amdgcn_s_barrier();
    asm volatile("" ::: "memory");
    bu = (bu == 2) ? 0 : bu + 1;
    bu2 = (bu2 == 2) ? 0 : bu2 + 1;
  }

#pragma unroll
  for (int mf = 0; mf < MF; ++mf) {
#pragma unroll
    for (int nf = 0; nf < NF; ++nf) {
      int col = n0 + wc * 32 + nf * 16 + l15;
      float bv = bias[col];
#pragma unroll
      for (int j = 0; j < 4; ++j) {
        int row = m0 + wr * 64 + mf * 16 + l4 * 4 + j;
        size_t o = (size_t)row * N + col;
        float v = acc[mf][nf][j] + bv;
        if (EPI == 0) {
          ((__hip_bfloat16*)outp)[o] = __float2bfloat16(v);
        } else if (EPI == 1) {
          ((float*)outp)[o] = v + resid[o];
        } else {
          float a = 0.7978845608028654f * (v + 0.044715f * v * v * v);
          a = fminf(fmaxf(a, -15.f), 15.f);
          float e = __expf(2.f * a);
          float th = (e - 1.f) / (e + 1.f);
          ((__hip_bfloat16*)outp)[o] = __float2bfloat16(0.5f * v * (1.f + th));
        }
      }
    }
  }
}

// =======  GEMM256: 256x256 tile, 8 waves (2x4), per-wave 128x64 (MF=8, NF=4)  =======
template <int EPI>
__global__ __launch_bounds__(512, 1) void gemm256(
    const __hip_bfloat16* __restrict__ A, const __hip_bfloat16* __restrict__ Bt,
    const float* __restrict__ bias, const float* __restrict__ resid,
    void* __restrict__ outp, int M, int N, int K) {
  constexpr int BM = 256, BN = 256, MF = 8, NF = 4, WN = 4;
  __shared__ alignas(16) __hip_bfloat16 sA[2][BM * 64];
  __shared__ alignas(16) __hip_bfloat16 sB[2][BN * 64];
  const int tid = threadIdx.x;                 // 0..511
  const int lane = tid & 63, wave = tid >> 6;  // 8 waves
  const int l15 = lane & 15, l4 = lane >> 4;
  const int wr = wave / WN, wc = wave % WN;    // 2 x 4
  const int csw = (l15 & 7) << 3;

  const int gx = gridDim.x;
  int nwg = gx * gridDim.y;
  int flat = blockIdx.y * gx + blockIdx.x;
  int cpx = nwg >> 3;
  int swz = (flat & 7) * cpx + (flat >> 3);
  const int m0 = (swz / gx) * BM, n0 = (swz % gx) * BN;

  f32x4 z = {0.f, 0.f, 0.f, 0.f};
  f32x4 acc[MF][NF];
#pragma unroll
  for (int i = 0; i < MF; ++i)
#pragma unroll
    for (int j = 0; j < NF; ++j) acc[i][j] = z;

  auto stage = [&](int bu, int kt) {   // 4+4 VMEM instr / thread
#pragma unroll
    for (int it = 0; it < 4; ++it) {
      int idx = it * 512 + tid;        // 0..2047
      int r = idx >> 3, c = (idx & 7) * 8;
      int cs = c ^ ((r & 7) << 3);
      g2lds16(A + (size_t)(m0 + r) * K + kt + cs, (void*)(&sA[bu][idx * 8]));
      g2lds16(Bt + (size_t)(n0 + r) * K + kt + cs, (void*)(&sB[bu][idx * 8]));
    }
  };

  const int nk = K / 64;
  stage(0, 0);
  asm volatile("s_waitcnt vmcnt(0)" ::: "memory");
  __builtin_amdgcn_s_barrier();

  for (int j = 0; j < nk; ++j) {
    const int cur = j & 1;
    if (j + 1 < nk) stage(cur ^ 1, (j + 1) * 64);

    __builtin_amdgcn_s_setprio(1);
#pragma unroll
    for (int kk = 0; kk < 2; ++kk) {
      int col = (kk * 32 + l4 * 8) ^ csw;
      bf16x8 bfr[NF];
#pragma unroll
      for (int nf = 0; nf < NF; ++nf)
        bfr[nf] = *(const bf16x8*)(&sB[cur][(wc * 64 + nf * 16 + l15) * 64 + col]);
#pragma unroll
      for (int mf = 0; mf < MF; ++mf) {
        bf16x8 af = *(const bf16x8*)(&sA[cur][(wr * 128 + mf * 16 + l15) * 64 + col]);
#pragma unroll
        for (int nf = 0; nf < NF; ++nf)
          acc[mf][nf] =
              __builtin_amdgcn_mfma_f32_16x16x32_bf16(af, bfr[nf], acc[mf][nf], 0, 0, 0);
      }
    }
    __builtin_amdgcn_s_setprio(0);

    asm volatile("s_waitcnt lgkmcnt(0)" ::: "memory");
    __builtin_amdgcn_sched_barrier(0);
    asm volatile("s_waitcnt vmcnt(0)" ::: "memory");
    __builtin_amdgcn_s_barrier();
    asm volatile("" ::: "memory");
  }

#pragma unroll
  for (int mf = 0; mf < MF; ++mf) {
#pragma unroll
    for (int nf = 0; nf < NF; ++nf) {
      int col = n0 + wc * 64 + nf * 16 + l15;
      float bv = bias[col];
#pragma unroll
      for (int j = 0; j < 4; ++j) {
        int row = m0 + wr * 128 + mf * 16 + l4 * 4 + j;
        size_t o = (size_t)row * N + col;
        float v = acc[mf][nf][j] + bv;
        if (EPI == 0) {
          ((__hip_bfloat16*)outp)[o] = __float2bfloat16(v);
        } else if (EPI == 1) {
          ((float*)outp)[o] = v + resid[o];
        } else {
          float a = 0.7978845608028654f * (v + 0.044715f * v * v * v);
          a = fminf(fmaxf(a, -15.f), 15.f);
          float e = __expf(2.f * a);
          float th = (e - 1.f) / (e + 1.f);
          ((__hip_bfloat16*)outp)[o] = __float2bfloat16(0.5f * v * (1.f + th));
        }
      }
    }
  }
}

// ======  Flash attention: QBLK=256, KVBLK=128, SOFTWARE-PIPELINED sub-tiles  ========
// Phase overlap (T15 mechanism): compute QK(st0) AND QK(st1) first, then SM0+PV0,
// then SM1+PV1. QK1's MFMAs drain under SM0's VALU ops; PV0's MFMAs overlap SM1.
// Matrix and vector pipes run concurrently instead of alternating. Both sub-tiles'
// score regs live (+64 VGPR) -> launch_bounds(256,1) (occupancy is 1 wave/SIMD anyway).
__global__ __launch_bounds__(256, 1) void attn_kernel(
    const __hip_bfloat16* __restrict__ qkv, const __hip_bfloat16* __restrict__ vT,
    __hip_bfloat16* __restrict__ out) {
  __shared__ alignas(16) __hip_bfloat16 sK[2][2][64 * 64];
  __shared__ alignas(16) __hip_bfloat16 sV[2][2][64 * 64];
  const int tid = threadIdx.x, lane = tid & 63, wave = tid >> 6;
  const int l31 = lane & 31, hi = lane >> 5;
  const int bh = blockIdx.x, b = bh >> 4, h = bh & 15;   // bh fastest -> XCD locality
  const int q0 = blockIdx.y * 256;
  const int rsw = (l31 & 7) << 3;
  const float k2 = 0.125f * 1.44269504f;

  bf16x8 qfA[4], qfB[4];
  {
    int qrA = q0 + wave * 64 + l31;
    const size_t qbA = ((size_t)(b * S_ + qrA)) * (3 * D_) + h * DH_;
    const size_t qbB = qbA + (size_t)32 * (3 * D_);
#pragma unroll
    for (int ks = 0; ks < 4; ++ks) {
      bf16x8 qa = *(const bf16x8*)(qkv + qbA + ks * 16 + hi * 8);
      bf16x8 qb = *(const bf16x8*)(qkv + qbB + ks * 16 + hi * 8);
#pragma unroll
      for (int i = 0; i < 8; ++i) {
        qa[i] = (__bf16)((float)qa[i] * k2);
        qb[i] = (__bf16)((float)qb[i] * k2);
      }
      qfA[ks] = qa;
      qfB[ks] = qb;
    }
  }

  bf16x8 onesb;
#pragma unroll
  for (int i = 0; i < 8; ++i) onesb[i] = (__bf16)1.0f;

  f32x16 Z16;
#pragma unroll
  for (int r = 0; r < 16; ++r) Z16[r] = 0.f;

  f32x16 accA0 = Z16, accA1 = Z16, accLA = Z16;
  f32x16 accB0 = Z16, accB1 = Z16, accLB = Z16;

  const __hip_bfloat16* kg = qkv + (size_t)b * S_ * (3 * D_) + D_ + h * DH_;
  const __hip_bfloat16* vg = vT + (size_t)bh * DH_ * S_;

  auto stage = [&](int bu, int kv0) {   // 8 VMEM instr / thread
#pragma unroll
    for (int st = 0; st < 2; ++st) {
#pragma unroll
      for (int it = 0; it < 2; ++it) {
        int idx = it * 256 + tid;
        int r = idx >> 3;
        int c = (idx & 7) * 8;
        int cs = c ^ ((r & 7) << 3);
        g2lds16(kg + (size_t)(kv0 + st * 64 + r) * (3 * D_) + cs,
                (void*)(&sK[bu][st][idx * 8]));
        g2lds16(vg + (size_t)r * S_ + kv0 + st * 64 + cs,
                (void*)(&sV[bu][st][idx * 8]));
      }
    }
  };

  // QK^T over one 64-row sub-tile -> 4 score fragments
  auto qk = [&](const __hip_bfloat16* sKc, f32x16& s0, f32x16& s1,
                f32x16& s2, f32x16& s3) {
    {
      int colsw = (hi * 8) ^ rsw;
      bf16x8 kf0 = *(const bf16x8*)(&sKc[l31 * 64 + colsw]);
      bf16x8 kf1 = *(const bf16x8*)(&sKc[(32 + l31) * 64 + colsw]);
      s0 = __builtin_amdgcn_mfma_f32_32x32x16_bf16(kf0, qfA[0], Z16, 0, 0, 0);
      s1 = __builtin_amdgcn_mfma_f32_32x32x16_bf16(kf1, qfA[0], Z16, 0, 0, 0);
      s2 = __builtin_amdgcn_mfma_f32_32x32x16_bf16(kf0, qfB[0], Z16, 0, 0, 0);
      s3 = __builtin_amdgcn_mfma_f32_32x32x16_bf16(kf1, qfB[0], Z16, 0, 0, 0);
    }
#pragma unroll
    for (int ks = 1; ks < 4; ++ks) {
      int colsw = (ks * 16 + hi * 8) ^ rsw;
      bf16x8 kf0 = *(const bf16x8*)(&sKc[l31 * 64 + colsw]);
      bf16x8 kf1 = *(const bf16x8*)(&sKc[(32 + l31) * 64 + colsw]);
      s0 = __builtin_amdgcn_mfma_f32_32x32x16_bf16(kf0, qfA[ks], s0, 0, 0, 0);
      s1 = __builtin_amdgcn_mfma_f32_32x32x16_bf16(kf1, qfA[ks], s1, 0, 0, 0);
      s2 = __builtin_amdgcn_mfma_f32_32x32x16_bf16(kf0, qfB[ks], s2, 0, 0, 0);
      s3 = __builtin_amdgcn_mfma_f32_32x32x16_bf16(kf1, qfB[ks], s3, 0, 0, 0);
    }
  };

  // softmax-pack + PV for one sub-tile
  auto smpv = [&](const __hip_bfloat16* sVc, const f32x16& sA0, const f32x16& sA1,
                  const f32x16& sB0, const f32x16& sB1) {
    bf16x8 paA[4], paB[4];
#pragma unroll
    for (int g = 0; g < 2; ++g) {
      const f32x16& s0 = g ? sB0 : sA0;
      const f32x16& s1 = g ? sB1 : sA1;
      bf16x8* pa = g ? paB : paA;
#pragma unroll
      for (int kb = 0; kb < 2; ++kb) {
        const f32x16& s16 = kb ? s1 : s0;
#pragma unroll
        for (int ksb = 0; ksb < 2; ++ksb) {
          float p0 = fexp2(s16[8 * ksb + 0]);
          float p1 = fexp2(s16[8 * ksb + 1]);
          float p2 = fexp2(s16[8 * ksb + 2]);
          float p3 = fexp2(s16[8 * ksb + 3]);
          float p4 = fexp2(s16[8 * ksb + 4]);
          float p5 = fexp2(s16[8 * ksb + 5]);
          float p6 = fexp2(s16[8 * ksb + 6]);
          float p7 = fexp2(s16[8 * ksb + 7]);
          unsigned wa = pkbf16(p0, p1), wb = pkbf16(p2, p3);
          unsigned wc = pkbf16(p4, p5), wd = pkbf16(p6, p7);
          auto r1 = __builtin_amdgcn_permlane32_swap(wa, wc, false, false);
          auto r2 = __builtin_amdgcn_permlane32_swap(wb, wd, false, false);
          union { unsigned u[4]; bf16x8 v; } w;
          w.u[0] = r1[0]; w.u[1] = r2[0]; w.u[2] = r1[1]; w.u[3] = r2[1];
          pa[kb * 2 + ksb] = w.v;
        }
      }
    }
#pragma unroll
    for (int ksg = 0; ksg < 4; ++ksg) {
      int colsw = (ksg * 16 + hi * 8) ^ rsw;
      bf16x8 vf0 = *(const bf16x8*)(&sVc[l31 * 64 + colsw]);
      bf16x8 vf1 = *(const bf16x8*)(&sVc[(32 + l31) * 64 + colsw]);
      accA0 = __builtin_amdgcn_mfma_f32_32x32x16_bf16(paA[ksg], vf0, accA0, 0, 0, 0);
      accA1 = __builtin_amdgcn_mfma_f32_32x32x16_bf16(paA[ksg], vf1, accA1, 0, 0, 0);
      accLA = __builtin_amdgcn_mfma_f32_32x32x16_bf16(paA[ksg], onesb, accLA, 0, 0, 0);
      accB0 = __builtin_amdgcn_mfma_f32_32x32x16_bf16(paB[ksg], vf0, accB0, 0, 0, 0);
      accB1 = __builtin_amdgcn_mfma_f32_32x32x16_bf16(paB[ksg], vf1, accB1, 0, 0, 0);
      accLB = __builtin_amdgcn_mfma_f32_32x32x16_bf16(paB[ksg], onesb, accLB, 0, 0, 0);
    }
  };

  stage(0, 0);
  const int NT = S_ / 128;   // 16 iterations, one barrier each

  for (int t = 0; t < NT; ++t) {
    const int cur = t & 1;
    __syncthreads();
    if (t + 1 < NT) stage(cur ^ 1, (t + 1) * 128);

    // PIPELINE: QK0, QK1 issued back-to-back; then SM0+PV0 (overlaps QK1 drain);
    // then SM1+PV1 (SM1's VALU overlaps PV0's MFMAs).
    f32x16 s0A0, s0A1, s0B0, s0B1;   // sub-tile 0 scores
    f32x16 s1A0, s1A1, s1B0, s1B1;   // sub-tile 1 scores
    qk(sK[cur][0], s0A0, s0A1, s0B0, s0B1);
    qk(sK[cur][1], s1A0, s1A1, s1B0, s1B1);
    smpv(sV[cur][0], s0A0, s0A1, s0B0, s0B1);
    smpv(sV[cur][1], s1A0, s1A1, s1B0, s1B1);
  }

#pragma unroll
  for (int r = 0; r < 16; ++r) {
    int qrow = (r & 3) + 8 * (r >> 2) + 4 * hi;
    size_t obA = ((size_t)(b * S_ + q0 + wave * 64 + qrow)) * D_ + h * DH_ + l31;
    size_t obB = obA + (size_t)32 * D_;
    float irA = 1.0f / accLA[r];
    float irB = 1.0f / accLB[r];
    out[obA] = __float2bfloat16(accA0[r] * irA);
    out[obA + 32] = __float2bfloat16(accA1[r] * irA);
    out[obB] = __float2bfloat16(accB0[r] * irB);
    out[obB + 32] = __float2bfloat16(accB1[r] * irB);
  }
}

// ====================================================================================
extern "C" void kernel_launch(void* const* d_in, const int* in_sizes, int n_in,
                              void* d_out, int out_size, void* d_ws, size_t ws_size,
                              hipStream_t stream) {
  const float* x = (const float*)d_in[0];
  const float* ln1_g = (const float*)d_in[1];
  const float* ln1_b = (const float*)d_in[2];
  const float* Wqkv = (const float*)d_in[3];
  const float* bqkv = (const float*)d_in[4];
  const float* Wo = (const float*)d_in[5];
  const float* bo = (const float*)d_in[6];
  const float* ln2_g = (const float*)d_in[7];
  const float* ln2_b = (const float*)d_in[8];
  const float* W1 = (const float*)d_in[9];
  const float* b1 = (const float*)d_in[10];
  const float* W2 = (const float*)d_in[11];
  const float* b2 = (const float*)d_in[12];
  float* out = (float*)d_out;

  char* ws = (char*)d_ws;
  size_t off = 0;
  auto alloc = [&](size_t bytes) {
    void* p = ws + off;
    off += (bytes + 255) & ~(size_t)255;
    return p;
  };
  __hip_bfloat16* WqkvT = (__hip_bfloat16*)alloc((size_t)3 * D_ * D_ * 2);
  __hip_bfloat16* WoT = (__hip_bfloat16*)alloc((size_t)D_ * D_ * 2);
  __hip_bfloat16* W1T = (__hip_bfloat16*)alloc((size_t)FF_ * D_ * 2);
  __hip_bfloat16* W2T = (__hip_bfloat16*)alloc((size_t)D_ * FF_ * 2);
  __hip_bfloat16* h = (__hip_bfloat16*)alloc((size_t)MR_ * D_ * 2);
  __hip_bfloat16* qkv = (__hip_bfloat16*)alloc((size_t)MR_ * FF_ * 2);  // shared w/ ff
  __hip_bfloat16* ff = qkv;
  __hip_bfloat16* vT = (__hip_bfloat16*)alloc((size_t)B_ * H_ * DH_ * S_ * 2);
  __hip_bfloat16* attn_out = (__hip_bfloat16*)alloc((size_t)MR_ * D_ * 2);

  // 1. weight prep: all four transposes in one dispatch (12288 tiles)
  transpose_all<<<dim3(12288), 256, 0, stream>>>(Wqkv, WqkvT, Wo, WoT, W1, W1T, W2, W2T);
  // 2. LN1
  ln_kernel<<<MR_, 256, 0, stream>>>(x, ln1_g, ln1_b, h);
  // 3. QKV gemm with fused V-transpose: gemm4<3>, grid (24,32) = 768
  gemm4<3><<<dim3(3 * D_ / 128, MR_ / 128), 256, 0, stream>>>(
      h, WqkvT, bqkv, nullptr, qkv, vT, MR_, 3 * D_, D_);
  // 4. attention: KVBLK=128 pipelined, grid (B*H, S/256) = (32, 8)
  attn_kernel<<<dim3(B_ * H_, S_ / 256), 256, 0, stream>>>(qkv, vT, attn_out);
  // 5. Wo gemm + residual -> d_out (fp32): gemm64r3, grid (16,32) = 512
  gemm64r3<1><<<dim3(D_ / 64, MR_ / 128), 256, 0, stream>>>(
      attn_out, WoT, bo, x, out, MR_, D_, D_);
  // 6. LN2 (reuse h)
  ln_kernel<<<MR_, 256, 0, stream>>>(out, ln2_g, ln2_b, h);
  // 7. W1 gemm + gelu: gemm256, grid (16,16) = 256
  gemm256<2><<<dim3(FF_ / 256, MR_ / 256), 512, 0, stream>>>(
      h, W1T, b1, nullptr, ff, MR_, FF_, D_);
  // 8. W2 gemm + residual(d_out) -> d_out: gemm64r3, grid (16,32) = 512
  gemm64r3<1><<<dim3(D_ / 64, MR_ / 128), 256, 0, stream>>>(
      ff, W2T, b2, out, out, MR_, D_, FF_);
}

// Round 22
// 200.492 us; speedup vs baseline: 1.0112x; 1.0112x over previous
//
#include <hip/hip_runtime.h>
#include <hip/hip_bf16.h>
#include <cstdint>

#define D_ 1024
#define H_ 16
#define DH_ 64
#define FF_ 4096
#define B_ 2
#define S_ 2048
#define MR_ (B_ * S_)   // 4096 rows

typedef __bf16 bf16x8 __attribute__((ext_vector_type(8)));
typedef __bf16 bf16x4 __attribute__((ext_vector_type(4)));
typedef float f32x4 __attribute__((ext_vector_type(4)));
typedef float f32x16 __attribute__((ext_vector_type(16)));

// ---- async global->LDS, 16B per lane (linear dest in lane order) ----
__device__ __forceinline__ void g2lds16(const void* g, void* l) {
  __builtin_amdgcn_global_load_lds(
      (__attribute__((address_space(1))) void*)(uintptr_t)g,
      (__attribute__((address_space(3))) void*)(uint32_t)(uintptr_t)l,
      16, 0, 0);
}

// pack two f32 -> one u32 holding 2 bf16 (lo, hi)
__device__ __forceinline__ unsigned pkbf16(float lo, float hi) {
  unsigned r;
  asm("v_cvt_pk_bf16_f32 %0, %1, %2" : "=v"(r) : "v"(lo), "v"(hi));
  return r;
}

// raw v_exp_f32 (1 instr)
__device__ __forceinline__ float fexp2(float x) {
  return __builtin_amdgcn_exp2f(x);
}

// ==========  merged weight transpose + fp32->bf16 (all 4 weights, 1 dispatch) ======
__global__ __launch_bounds__(256) void transpose_all(
    const float* __restrict__ W0, __hip_bfloat16* __restrict__ T0,
    const float* __restrict__ W1p, __hip_bfloat16* __restrict__ T1,
    const float* __restrict__ W2p, __hip_bfloat16* __restrict__ T2,
    const float* __restrict__ W3p, __hip_bfloat16* __restrict__ T3) {
  __shared__ float t[32][33];
  int ti = blockIdx.x;
  const float* W;
  __hip_bfloat16* Wt;
  int K, N, loc;
  if (ti < 3072)      { W = W0;  Wt = T0; K = 1024; N = 3072; loc = ti; }
  else if (ti < 4096) { W = W1p; Wt = T1; K = 1024; N = 1024; loc = ti - 3072; }
  else if (ti < 8192) { W = W2p; Wt = T2; K = 1024; N = 4096; loc = ti - 4096; }
  else                { W = W3p; Wt = T3; K = 4096; N = 1024; loc = ti - 8192; }
  int ntn = N >> 5;
  int bx = (loc % ntn) * 32;   // n
  int by = (loc / ntn) * 32;   // k
  int tx = threadIdx.x & 31, ty = threadIdx.x >> 5;  // 32 x 8
#pragma unroll
  for (int i = 0; i < 4; ++i)
    t[ty + 8 * i][tx] = W[(size_t)(by + ty + 8 * i) * N + bx + tx];
  __syncthreads();
#pragma unroll
  for (int i = 0; i < 4; ++i)
    Wt[(size_t)(bx + ty + 8 * i) * K + by + tx] = __float2bfloat16(t[tx][ty + 8 * i]);
}

// ==========================  LayerNorm (fp32 in, bf16 out)  ========================
__global__ __launch_bounds__(256) void ln_kernel(
    const float* __restrict__ x, const float* __restrict__ g,
    const float* __restrict__ b, __hip_bfloat16* __restrict__ out) {
  int row = blockIdx.x;
  const float4* xr = (const float4*)(x + (size_t)row * D_);
  float4 v = xr[threadIdx.x];
  float s = v.x + v.y + v.z + v.w;
  float ss = v.x * v.x + v.y * v.y + v.z * v.z + v.w * v.w;
#pragma unroll
  for (int m = 1; m < 64; m <<= 1) {
    s += __shfl_xor(s, m);
    ss += __shfl_xor(ss, m);
  }
  __shared__ float rs[4], rss[4];
  int wave = threadIdx.x >> 6, lane = threadIdx.x & 63;
  if (lane == 0) { rs[wave] = s; rss[wave] = ss; }
  __syncthreads();
  s = rs[0] + rs[1] + rs[2] + rs[3];
  ss = rss[0] + rss[1] + rss[2] + rss[3];
  float mean = s * (1.0f / D_);
  float var = ss * (1.0f / D_) - mean * mean;
  float inv = rsqrtf(var + 1e-5f);
  int c = threadIdx.x * 4;
  float4 gv = ((const float4*)g)[threadIdx.x];
  float4 bv = ((const float4*)b)[threadIdx.x];
  __hip_bfloat16* o = out + (size_t)row * D_ + c;
  o[0] = __float2bfloat16((v.x - mean) * inv * gv.x + bv.x);
  o[1] = __float2bfloat16((v.y - mean) * inv * gv.y + bv.y);
  o[2] = __float2bfloat16((v.z - mean) * inv * gv.z + bv.z);
  o[3] = __float2bfloat16((v.w - mean) * inv * gv.w + bv.w);
}

// =======  GEMM4: 128x128 tile, 4 waves (2x2), per-wave 64x64 (MF=NF=4)  =============
// EPI 0: bf16 +bias;  1: f32 +bias+resid;  2: bf16 +bias+gelu;
// EPI 3: QKV fused — V cols (>=2D) -> vt transposed ([b,h,dh,s], packed bf16x4).
template <int EPI>
__global__ __launch_bounds__(256) void gemm4(
    const __hip_bfloat16* __restrict__ A, const __hip_bfloat16* __restrict__ Bt,
    const float* __restrict__ bias, const float* __restrict__ resid,
    void* __restrict__ outp, __hip_bfloat16* __restrict__ vt, int M, int N, int K) {
  constexpr int BM = 128, BN = 128, MF = 4, NF = 4;
  __shared__ alignas(16) __hip_bfloat16 sA[2][BM * 64];
  __shared__ alignas(16) __hip_bfloat16 sB[2][BN * 64];
  const int tid = threadIdx.x;                 // 0..255
  const int lane = tid & 63, wave = tid >> 6;  // 4 waves
  const int l15 = lane & 15, l4 = lane >> 4;
  const int wr = wave >> 1, wc = wave & 1;     // 2x2
  const int csw = (l15 & 7) << 3;

  const int gx = gridDim.x;
  int nwg = gx * gridDim.y;
  int flat = blockIdx.y * gx + blockIdx.x;
  int cpx = nwg >> 3;
  int swz = (flat & 7) * cpx + (flat >> 3);
  const int m0 = (swz / gx) * BM, n0 = (swz % gx) * BN;

  f32x4 z = {0.f, 0.f, 0.f, 0.f};
  f32x4 acc[MF][NF];
#pragma unroll
  for (int i = 0; i < MF; ++i)
#pragma unroll
    for (int j = 0; j < NF; ++j) acc[i][j] = z;

  auto stage = [&](int bu, int kt) {   // 4+4 VMEM instr / thread
#pragma unroll
    for (int it = 0; it < 4; ++it) {
      int idx = it * 256 + tid;
      int r = idx >> 3, c = (idx & 7) * 8;
      int cs = c ^ ((r & 7) << 3);
      g2lds16(A + (size_t)(m0 + r) * K + kt + cs, (void*)(&sA[bu][idx * 8]));
      g2lds16(Bt + (size_t)(n0 + r) * K + kt + cs, (void*)(&sB[bu][idx * 8]));
    }
  };

  const int nk = K / 64;
  stage(0, 0);
  asm volatile("s_waitcnt vmcnt(0)" ::: "memory");
  __builtin_amdgcn_s_barrier();

  for (int j = 0; j < nk; ++j) {
    const int cur = j & 1;
    if (j + 1 < nk) stage(cur ^ 1, (j + 1) * 64);

    __builtin_amdgcn_s_setprio(1);
#pragma unroll
    for (int kk = 0; kk < 2; ++kk) {
      int col = (kk * 32 + l4 * 8) ^ csw;
      bf16x8 bfr[NF];
#pragma unroll
      for (int nf = 0; nf < NF; ++nf)
        bfr[nf] = *(const bf16x8*)(&sB[cur][(wc * 64 + nf * 16 + l15) * 64 + col]);
#pragma unroll
      for (int mf = 0; mf < MF; ++mf) {
        bf16x8 af = *(const bf16x8*)(&sA[cur][(wr * 64 + mf * 16 + l15) * 64 + col]);
#pragma unroll
        for (int nf = 0; nf < NF; ++nf)
          acc[mf][nf] =
              __builtin_amdgcn_mfma_f32_16x16x32_bf16(af, bfr[nf], acc[mf][nf], 0, 0, 0);
      }
    }
    __builtin_amdgcn_s_setprio(0);

    asm volatile("s_waitcnt lgkmcnt(0)" ::: "memory");
    __builtin_amdgcn_sched_barrier(0);
    asm volatile("s_waitcnt vmcnt(0)" ::: "memory");
    __builtin_amdgcn_s_barrier();
    asm volatile("" ::: "memory");
  }

#pragma unroll
  for (int mf = 0; mf < MF; ++mf) {
#pragma unroll
    for (int nf = 0; nf < NF; ++nf) {
      int col = n0 + wc * 64 + nf * 16 + l15;
      float bv = bias[col];
      if (EPI == 3 && col >= 2 * D_) {
        int d = col - 2 * D_;
        int srow0 = m0 + wr * 64 + mf * 16 + l4 * 4;
        int bb = srow0 >> 11, s0 = srow0 & (S_ - 1);
        bf16x4 ov;
#pragma unroll
        for (int j = 0; j < 4; ++j) ov[j] = (__bf16)(acc[mf][nf][j] + bv);
        *(bf16x4*)(vt + ((size_t)(bb * H_ + (d >> 6)) * DH_ + (d & 63)) * S_ + s0) = ov;
      } else {
#pragma unroll
        for (int j = 0; j < 4; ++j) {
          int row = m0 + wr * 64 + mf * 16 + l4 * 4 + j;
          size_t o = (size_t)row * N + col;
          float v = acc[mf][nf][j] + bv;
          if (EPI == 0 || EPI == 3) {
            ((__hip_bfloat16*)outp)[o] = __float2bfloat16(v);
          } else if (EPI == 1) {
            ((float*)outp)[o] = v + resid[o];
          } else {
            float a = 0.7978845608028654f * (v + 0.044715f * v * v * v);
            a = fminf(fmaxf(a, -15.f), 15.f);
            float e = __expf(2.f * a);
            float th = (e - 1.f) / (e + 1.f);
            ((__hip_bfloat16*)outp)[o] = __float2bfloat16(0.5f * v * (1.f + th));
          }
        }
      }
    }
  }
}

// ====  GEMM64R3: 128x64 tile, 4 waves (2x2), 3-buffer ring + counted vmcnt(6)  ======
template <int EPI>
__global__ __launch_bounds__(256) void gemm64r3(
    const __hip_bfloat16* __restrict__ A, const __hip_bfloat16* __restrict__ Bt,
    const float* __restrict__ bias, const float* __restrict__ resid,
    void* __restrict__ outp, int M, int N, int K) {
  constexpr int BM = 128, BN = 64, MF = 4, NF = 2;
  __shared__ alignas(16) __hip_bfloat16 sA[3][BM * 64];
  __shared__ alignas(16) __hip_bfloat16 sB[3][BN * 64];
  const int tid = threadIdx.x;                 // 0..255
  const int lane = tid & 63, wave = tid >> 6;  // 4 waves
  const int l15 = lane & 15, l4 = lane >> 4;
  const int wr = wave >> 1, wc = wave & 1;     // 2x2
  const int csw = (l15 & 7) << 3;

  const int gx = gridDim.x;
  int nwg = gx * gridDim.y;
  int flat = blockIdx.y * gx + blockIdx.x;
  int cpx = nwg >> 3;
  int swz = (flat & 7) * cpx + (flat >> 3);
  const int m0 = (swz / gx) * BM, n0 = (swz % gx) * BN;

  f32x4 z = {0.f, 0.f, 0.f, 0.f};
  f32x4 acc[MF][NF];
#pragma unroll
  for (int i = 0; i < MF; ++i)
#pragma unroll
    for (int j = 0; j < NF; ++j) acc[i][j] = z;

  auto stage = [&](int bu, int kt) {   // 4+2 = 6 VMEM instr / thread
#pragma unroll
    for (int it = 0; it < 4; ++it) {
      int idx = it * 256 + tid;
      int r = idx >> 3, c = (idx & 7) * 8;
      int cs = c ^ ((r & 7) << 3);
      g2lds16(A + (size_t)(m0 + r) * K + kt + cs, (void*)(&sA[bu][idx * 8]));
    }
#pragma unroll
    for (int it = 0; it < 2; ++it) {
      int idx = it * 256 + tid;
      int r = idx >> 3, c = (idx & 7) * 8;
      int cs = c ^ ((r & 7) << 3);
      g2lds16(Bt + (size_t)(n0 + r) * K + kt + cs, (void*)(&sB[bu][idx * 8]));
    }
  };

  const int nk = K / 64;
  stage(0, 0);
  stage(1, 64);
  asm volatile("s_waitcnt vmcnt(6)" ::: "memory");
  __builtin_amdgcn_s_barrier();

  int bu = 0, bu2 = 2;
  for (int j = 0; j < nk; ++j) {
    const bool pf = (j + 2) < nk;
    if (pf) stage(bu2, (j + 2) * 64);

    __builtin_amdgcn_s_setprio(1);
#pragma unroll
    for (int kk = 0; kk < 2; ++kk) {
      int col = (kk * 32 + l4 * 8) ^ csw;
      bf16x8 bfr[NF];
#pragma unroll
      for (int nf = 0; nf < NF; ++nf)
        bfr[nf] = *(const bf16x8*)(&sB[bu][(wc * 32 + nf * 16 + l15) * 64 + col]);
#pragma unroll
      for (int mf = 0; mf < MF; ++mf) {
        bf16x8 af = *(const bf16x8*)(&sA[bu][(wr * 64 + mf * 16 + l15) * 64 + col]);
#pragma unroll
        for (int nf = 0; nf < NF; ++nf)
          acc[mf][nf] =
              __builtin_amdgcn_mfma_f32_16x16x32_bf16(af, bfr[nf], acc[mf][nf], 0, 0, 0);
      }
    }
    __builtin_amdgcn_s_setprio(0);

    asm volatile("s_waitcnt lgkmcnt(0)" ::: "memory");
    __builtin_amdgcn_sched_barrier(0);
    if (pf)
      asm volatile("s_waitcnt vmcnt(6)" ::: "memory");
    else
      asm volatile("s_waitcnt vmcnt(0)" ::: "memory");
    __builtin_amdgcn_s_barrier();
    asm volatile("" ::: "memory");
    bu = (bu == 2) ? 0 : bu + 1;
    bu2 = (bu2 == 2) ? 0 : bu2 + 1;
  }

#pragma unroll
  for (int mf = 0; mf < MF; ++mf) {
#pragma unroll
    for (int nf = 0; nf < NF; ++nf) {
      int col = n0 + wc * 32 + nf * 16 + l15;
      float bv = bias[col];
#pragma unroll
      for (int j = 0; j < 4; ++j) {
        int row = m0 + wr * 64 + mf * 16 + l4 * 4 + j;
        size_t o = (size_t)row * N + col;
        float v = acc[mf][nf][j] + bv;
        if (EPI == 0) {
          ((__hip_bfloat16*)outp)[o] = __float2bfloat16(v);
        } else if (EPI == 1) {
          ((float*)outp)[o] = v + resid[o];
        } else {
          float a = 0.7978845608028654f * (v + 0.044715f * v * v * v);
          a = fminf(fmaxf(a, -15.f), 15.f);
          float e = __expf(2.f * a);
          float th = (e - 1.f) / (e + 1.f);
          ((__hip_bfloat16*)outp)[o] = __float2bfloat16(0.5f * v * (1.f + th));
        }
      }
    }
  }
}

// =======  GEMM256: 256x256 tile, 8 waves (2x4), per-wave 128x64 (MF=8, NF=4)  =======
template <int EPI>
__global__ __launch_bounds__(512, 1) void gemm256(
    const __hip_bfloat16* __restrict__ A, const __hip_bfloat16* __restrict__ Bt,
    const float* __restrict__ bias, const float* __restrict__ resid,
    void* __restrict__ outp, int M, int N, int K) {
  constexpr int BM = 256, BN = 256, MF = 8, NF = 4, WN = 4;
  __shared__ alignas(16) __hip_bfloat16 sA[2][BM * 64];
  __shared__ alignas(16) __hip_bfloat16 sB[2][BN * 64];
  const int tid = threadIdx.x;                 // 0..511
  const int lane = tid & 63, wave = tid >> 6;  // 8 waves
  const int l15 = lane & 15, l4 = lane >> 4;
  const int wr = wave / WN, wc = wave % WN;    // 2 x 4
  const int csw = (l15 & 7) << 3;

  const int gx = gridDim.x;
  int nwg = gx * gridDim.y;
  int flat = blockIdx.y * gx + blockIdx.x;
  int cpx = nwg >> 3;
  int swz = (flat & 7) * cpx + (flat >> 3);
  const int m0 = (swz / gx) * BM, n0 = (swz % gx) * BN;

  f32x4 z = {0.f, 0.f, 0.f, 0.f};
  f32x4 acc[MF][NF];
#pragma unroll
  for (int i = 0; i < MF; ++i)
#pragma unroll
    for (int j = 0; j < NF; ++j) acc[i][j] = z;

  auto stage = [&](int bu, int kt) {   // 4+4 VMEM instr / thread
#pragma unroll
    for (int it = 0; it < 4; ++it) {
      int idx = it * 512 + tid;        // 0..2047
      int r = idx >> 3, c = (idx & 7) * 8;
      int cs = c ^ ((r & 7) << 3);
      g2lds16(A + (size_t)(m0 + r) * K + kt + cs, (void*)(&sA[bu][idx * 8]));
      g2lds16(Bt + (size_t)(n0 + r) * K + kt + cs, (void*)(&sB[bu][idx * 8]));
    }
  };

  const int nk = K / 64;
  stage(0, 0);
  asm volatile("s_waitcnt vmcnt(0)" ::: "memory");
  __builtin_amdgcn_s_barrier();

  for (int j = 0; j < nk; ++j) {
    const int cur = j & 1;
    if (j + 1 < nk) stage(cur ^ 1, (j + 1) * 64);

    __builtin_amdgcn_s_setprio(1);
#pragma unroll
    for (int kk = 0; kk < 2; ++kk) {
      int col = (kk * 32 + l4 * 8) ^ csw;
      bf16x8 bfr[NF];
#pragma unroll
      for (int nf = 0; nf < NF; ++nf)
        bfr[nf] = *(const bf16x8*)(&sB[cur][(wc * 64 + nf * 16 + l15) * 64 + col]);
#pragma unroll
      for (int mf = 0; mf < MF; ++mf) {
        bf16x8 af = *(const bf16x8*)(&sA[cur][(wr * 128 + mf * 16 + l15) * 64 + col]);
#pragma unroll
        for (int nf = 0; nf < NF; ++nf)
          acc[mf][nf] =
              __builtin_amdgcn_mfma_f32_16x16x32_bf16(af, bfr[nf], acc[mf][nf], 0, 0, 0);
      }
    }
    __builtin_amdgcn_s_setprio(0);

    asm volatile("s_waitcnt lgkmcnt(0)" ::: "memory");
    __builtin_amdgcn_sched_barrier(0);
    asm volatile("s_waitcnt vmcnt(0)" ::: "memory");
    __builtin_amdgcn_s_barrier();
    asm volatile("" ::: "memory");
  }

#pragma unroll
  for (int mf = 0; mf < MF; ++mf) {
#pragma unroll
    for (int nf = 0; nf < NF; ++nf) {
      int col = n0 + wc * 64 + nf * 16 + l15;
      float bv = bias[col];
#pragma unroll
      for (int j = 0; j < 4; ++j) {
        int row = m0 + wr * 128 + mf * 16 + l4 * 4 + j;
        size_t o = (size_t)row * N + col;
        float v = acc[mf][nf][j] + bv;
        if (EPI == 0) {
          ((__hip_bfloat16*)outp)[o] = __float2bfloat16(v);
        } else if (EPI == 1) {
          ((float*)outp)[o] = v + resid[o];
        } else {
          float a = 0.7978845608028654f * (v + 0.044715f * v * v * v);
          a = fminf(fmaxf(a, -15.f), 15.f);
          float e = __expf(2.f * a);
          float th = (e - 1.f) / (e + 1.f);
          ((__hip_bfloat16*)outp)[o] = __float2bfloat16(0.5f * v * (1.f + th));
        }
      }
    }
  }
}

// ======  Flash attention: QBLK=256, KVBLK=128 (2 sub-tiles per barrier)  ============
// R20 config (best verified). Grid (B*H, S/256): same-head blocks on same XCD.
__global__ __launch_bounds__(256, 2) void attn_kernel(
    const __hip_bfloat16* __restrict__ qkv, const __hip_bfloat16* __restrict__ vT,
    __hip_bfloat16* __restrict__ out) {
  __shared__ alignas(16) __hip_bfloat16 sK[2][2][64 * 64];
  __shared__ alignas(16) __hip_bfloat16 sV[2][2][64 * 64];
  const int tid = threadIdx.x, lane = tid & 63, wave = tid >> 6;
  const int l31 = lane & 31, hi = lane >> 5;
  const int bh = blockIdx.x, b = bh >> 4, h = bh & 15;   // bh fastest -> XCD locality
  const int q0 = blockIdx.y * 256;
  const int rsw = (l31 & 7) << 3;
  const float k2 = 0.125f * 1.44269504f;

  bf16x8 qfA[4], qfB[4];
  {
    int qrA = q0 + wave * 64 + l31;
    const size_t qbA = ((size_t)(b * S_ + qrA)) * (3 * D_) + h * DH_;
    const size_t qbB = qbA + (size_t)32 * (3 * D_);
#pragma unroll
    for (int ks = 0; ks < 4; ++ks) {
      bf16x8 qa = *(const bf16x8*)(qkv + qbA + ks * 16 + hi * 8);
      bf16x8 qb = *(const bf16x8*)(qkv + qbB + ks * 16 + hi * 8);
#pragma unroll
      for (int i = 0; i < 8; ++i) {
        qa[i] = (__bf16)((float)qa[i] * k2);
        qb[i] = (__bf16)((float)qb[i] * k2);
      }
      qfA[ks] = qa;
      qfB[ks] = qb;
    }
  }

  bf16x8 onesb;
#pragma unroll
  for (int i = 0; i < 8; ++i) onesb[i] = (__bf16)1.0f;

  f32x16 Z16;
#pragma unroll
  for (int r = 0; r < 16; ++r) Z16[r] = 0.f;

  f32x16 accA0 = Z16, accA1 = Z16, accLA = Z16;
  f32x16 accB0 = Z16, accB1 = Z16, accLB = Z16;

  const __hip_bfloat16* kg = qkv + (size_t)b * S_ * (3 * D_) + D_ + h * DH_;
  const __hip_bfloat16* vg = vT + (size_t)bh * DH_ * S_;

  // stage 128 kv rows: two 64-row sub-tiles (identical [64][64] layout each)
  auto stage = [&](int bu, int kv0) {   // 8 VMEM instr / thread
#pragma unroll
    for (int st = 0; st < 2; ++st) {
#pragma unroll
      for (int it = 0; it < 2; ++it) {
        int idx = it * 256 + tid;
        int r = idx >> 3;
        int c = (idx & 7) * 8;
        int cs = c ^ ((r & 7) << 3);
        g2lds16(kg + (size_t)(kv0 + st * 64 + r) * (3 * D_) + cs,
                (void*)(&sK[bu][st][idx * 8]));
        g2lds16(vg + (size_t)r * S_ + kv0 + st * 64 + cs,
                (void*)(&sV[bu][st][idx * 8]));
      }
    }
  };

  stage(0, 0);
  const int NT = S_ / 128;   // 16 iterations, one barrier each

  for (int t = 0; t < NT; ++t) {
    const int cur = t & 1;
    __syncthreads();
    if (t + 1 < NT) stage(cur ^ 1, (t + 1) * 128);

#pragma unroll
    for (int st = 0; st < 2; ++st) {
      const __hip_bfloat16* sKc = sK[cur][st];
      const __hip_bfloat16* sVc = sV[cur][st];

      f32x16 sfA0, sfA1, sfB0, sfB1;
      __builtin_amdgcn_s_setprio(1);
      {
        int colsw = (hi * 8) ^ rsw;
        bf16x8 kf0 = *(const bf16x8*)(&sKc[l31 * 64 + colsw]);
        bf16x8 kf1 = *(const bf16x8*)(&sKc[(32 + l31) * 64 + colsw]);
        sfA0 = __builtin_amdgcn_mfma_f32_32x32x16_bf16(kf0, qfA[0], Z16, 0, 0, 0);
        sfA1 = __builtin_amdgcn_mfma_f32_32x32x16_bf16(kf1, qfA[0], Z16, 0, 0, 0);
        sfB0 = __builtin_amdgcn_mfma_f32_32x32x16_bf16(kf0, qfB[0], Z16, 0, 0, 0);
        sfB1 = __builtin_amdgcn_mfma_f32_32x32x16_bf16(kf1, qfB[0], Z16, 0, 0, 0);
      }
#pragma unroll
      for (int ks = 1; ks < 4; ++ks) {
        int colsw = (ks * 16 + hi * 8) ^ rsw;
        bf16x8 kf0 = *(const bf16x8*)(&sKc[l31 * 64 + colsw]);
        bf16x8 kf1 = *(const bf16x8*)(&sKc[(32 + l31) * 64 + colsw]);
        sfA0 = __builtin_amdgcn_mfma_f32_32x32x16_bf16(kf0, qfA[ks], sfA0, 0, 0, 0);
        sfA1 = __builtin_amdgcn_mfma_f32_32x32x16_bf16(kf1, qfA[ks], sfA1, 0, 0, 0);
        sfB0 = __builtin_amdgcn_mfma_f32_32x32x16_bf16(kf0, qfB[ks], sfB0, 0, 0, 0);
        sfB1 = __builtin_amdgcn_mfma_f32_32x32x16_bf16(kf1, qfB[ks], sfB1, 0, 0, 0);
      }
      __builtin_amdgcn_s_setprio(0);

      bf16x8 paA[4], paB[4];
#pragma unroll
      for (int g = 0; g < 2; ++g) {
        const f32x16& s0 = g ? sfB0 : sfA0;
        const f32x16& s1 = g ? sfB1 : sfA1;
        bf16x8* pa = g ? paB : paA;
#pragma unroll
        for (int kb = 0; kb < 2; ++kb) {
          const f32x16& s16 = kb ? s1 : s0;
#pragma unroll
          for (int ksb = 0; ksb < 2; ++ksb) {
            float p0 = fexp2(s16[8 * ksb + 0]);
            float p1 = fexp2(s16[8 * ksb + 1]);
            float p2 = fexp2(s16[8 * ksb + 2]);
            float p3 = fexp2(s16[8 * ksb + 3]);
            float p4 = fexp2(s16[8 * ksb + 4]);
            float p5 = fexp2(s16[8 * ksb + 5]);
            float p6 = fexp2(s16[8 * ksb + 6]);
            float p7 = fexp2(s16[8 * ksb + 7]);
            unsigned wa = pkbf16(p0, p1), wb = pkbf16(p2, p3);
            unsigned wc = pkbf16(p4, p5), wd = pkbf16(p6, p7);
            auto r1 = __builtin_amdgcn_permlane32_swap(wa, wc, false, false);
            auto r2 = __builtin_amdgcn_permlane32_swap(wb, wd, false, false);
            union { unsigned u[4]; bf16x8 v; } w;
            w.u[0] = r1[0]; w.u[1] = r2[0]; w.u[2] = r1[1]; w.u[3] = r2[1];
            pa[kb * 2 + ksb] = w.v;
          }
        }
      }

      __builtin_amdgcn_s_setprio(1);
#pragma unroll
      for (int ksg = 0; ksg < 4; ++ksg) {
        int colsw = (ksg * 16 + hi * 8) ^ rsw;
        bf16x8 vf0 = *(const bf16x8*)(&sVc[l31 * 64 + colsw]);
        bf16x8 vf1 = *(const bf16x8*)(&sVc[(32 + l31) * 64 + colsw]);
        accA0 = __builtin_amdgcn_mfma_f32_32x32x16_bf16(paA[ksg], vf0, accA0, 0, 0, 0);
        accA1 = __builtin_amdgcn_mfma_f32_32x32x16_bf16(paA[ksg], vf1, accA1, 0, 0, 0);
        accLA = __builtin_amdgcn_mfma_f32_32x32x16_bf16(paA[ksg], onesb, accLA, 0, 0, 0);
        accB0 = __builtin_amdgcn_mfma_f32_32x32x16_bf16(paB[ksg], vf0, accB0, 0, 0, 0);
        accB1 = __builtin_amdgcn_mfma_f32_32x32x16_bf16(paB[ksg], vf1, accB1, 0, 0, 0);
        accLB = __builtin_amdgcn_mfma_f32_32x32x16_bf16(paB[ksg], onesb, accLB, 0, 0, 0);
      }
      __builtin_amdgcn_s_setprio(0);
    }
  }

#pragma unroll
  for (int r = 0; r < 16; ++r) {
    int qrow = (r & 3) + 8 * (r >> 2) + 4 * hi;
    size_t obA = ((size_t)(b * S_ + q0 + wave * 64 + qrow)) * D_ + h * DH_ + l31;
    size_t obB = obA + (size_t)32 * D_;
    float irA = 1.0f / accLA[r];
    float irB = 1.0f / accLB[r];
    out[obA] = __float2bfloat16(accA0[r] * irA);
    out[obA + 32] = __float2bfloat16(accA1[r] * irA);
    out[obB] = __float2bfloat16(accB0[r] * irB);
    out[obB + 32] = __float2bfloat16(accB1[r] * irB);
  }
}

// ====================================================================================
extern "C" void kernel_launch(void* const* d_in, const int* in_sizes, int n_in,
                              void* d_out, int out_size, void* d_ws, size_t ws_size,
                              hipStream_t stream) {
  const float* x = (const float*)d_in[0];
  const float* ln1_g = (const float*)d_in[1];
  const float* ln1_b = (const float*)d_in[2];
  const float* Wqkv = (const float*)d_in[3];
  const float* bqkv = (const float*)d_in[4];
  const float* Wo = (const float*)d_in[5];
  const float* bo = (const float*)d_in[6];
  const float* ln2_g = (const float*)d_in[7];
  const float* ln2_b = (const float*)d_in[8];
  const float* W1 = (const float*)d_in[9];
  const float* b1 = (const float*)d_in[10];
  const float* W2 = (const float*)d_in[11];
  const float* b2 = (const float*)d_in[12];
  float* out = (float*)d_out;

  char* ws = (char*)d_ws;
  size_t off = 0;
  auto alloc = [&](size_t bytes) {
    void* p = ws + off;
    off += (bytes + 255) & ~(size_t)255;
    return p;
  };
  __hip_bfloat16* WqkvT = (__hip_bfloat16*)alloc((size_t)3 * D_ * D_ * 2);
  __hip_bfloat16* WoT = (__hip_bfloat16*)alloc((size_t)D_ * D_ * 2);
  __hip_bfloat16* W1T = (__hip_bfloat16*)alloc((size_t)FF_ * D_ * 2);
  __hip_bfloat16* W2T = (__hip_bfloat16*)alloc((size_t)D_ * FF_ * 2);
  __hip_bfloat16* h = (__hip_bfloat16*)alloc((size_t)MR_ * D_ * 2);
  __hip_bfloat16* qkv = (__hip_bfloat16*)alloc((size_t)MR_ * FF_ * 2);  // shared w/ ff
  __hip_bfloat16* ff = qkv;
  __hip_bfloat16* vT = (__hip_bfloat16*)alloc((size_t)B_ * H_ * DH_ * S_ * 2);
  __hip_bfloat16* attn_out = (__hip_bfloat16*)alloc((size_t)MR_ * D_ * 2);

  // 1. weight prep: all four transposes in one dispatch (12288 tiles)
  transpose_all<<<dim3(12288), 256, 0, stream>>>(Wqkv, WqkvT, Wo, WoT, W1, W1T, W2, W2T);
  // 2. LN1
  ln_kernel<<<MR_, 256, 0, stream>>>(x, ln1_g, ln1_b, h);
  // 3. QKV gemm with fused V-transpose: gemm4<3>, grid (24,32) = 768
  gemm4<3><<<dim3(3 * D_ / 128, MR_ / 128), 256, 0, stream>>>(
      h, WqkvT, bqkv, nullptr, qkv, vT, MR_, 3 * D_, D_);
  // 4. attention: KVBLK=128, grid (B*H, S/256) = (32, 8)
  attn_kernel<<<dim3(B_ * H_, S_ / 256), 256, 0, stream>>>(qkv, vT, attn_out);
  // 5. Wo gemm + residual -> d_out (fp32): gemm64r3, grid (16,32) = 512
  gemm64r3<1><<<dim3(D_ / 64, MR_ / 128), 256, 0, stream>>>(
      attn_out, WoT, bo, x, out, MR_, D_, D_);
  // 6. LN2 (reuse h)
  ln_kernel<<<MR_, 256, 0, stream>>>(out, ln2_g, ln2_b, h);
  // 7. W1 gemm + gelu: gemm256, grid (16,16) = 256
  gemm256<2><<<dim3(FF_ / 256, MR_ / 256), 512, 0, stream>>>(
      h, W1T, b1, nullptr, ff, MR_, FF_, D_);
  // 8. W2 gemm + residual(d_out) -> d_out: gemm64r3, grid (16,32) = 512
  gemm64r3<1><<<dim3(D_ / 64, MR_ / 128), 256, 0, stream>>>(
      ff, W2T, b2, out, out, MR_, D_, FF_);
}